// Round 1
// baseline (472.233 us; speedup 1.0000x reference)
//
#include <hip/hip_runtime.h>
#include <stdint.h>

typedef __bf16 bf16x8 __attribute__((ext_vector_type(8)));
typedef float f32x4 __attribute__((ext_vector_type(4)));

// ---- workspace byte offsets ----
// [0, 3932160)            gwT per level (bf16, [512][C]), offsets 262144*((1<<l)-1)
#define OFF_PMEAN  3932160u   // 3840 floats
#define OFF_TEXT   3947520u   // 4096 floats (l2-normalized text)
#define OFF_U      3963904u   // 4 lvl * 4 seg * 512 floats
#define OFF_GG     3996672u
#define OFF_BB     4029440u
#define OFF_SCAL   4062208u   // [0..3] sum_proto, [4..7] sumsq_proto, [8] scale, [16..79] partials
#define OFF_LOGITS 4062720u   // 8192*32 floats
// total 5,111,296 bytes

__host__ __device__ __forceinline__ size_t gwt_off(int l) {
  return (size_t)262144u * (size_t)((1u << l) - 1u);
}
__device__ __forceinline__ int pm_off(int l) { return 256 * ((1 << l) - 1); }

__device__ __forceinline__ unsigned short f2bf(float x) {
  return (unsigned short)((__float_as_uint(x) + 0x8000u) >> 16);
}
__device__ __forceinline__ unsigned pack2(float a, float b) {
  return ((__float_as_uint(a) + 0x8000u) >> 16) |
         ((__float_as_uint(b) + 0x8000u) & 0xffff0000u);
}
__device__ __forceinline__ void async_load16(const void* g, void* l) {
  __builtin_amdgcn_global_load_lds((const __attribute__((address_space(1))) void*)g,
                                   (__attribute__((address_space(3))) void*)l,
                                   16, 0, 0);
}

// ---------------- prep1: proto means + text l2norm + scale ----------------
__global__ void prep1(const float* pr0, const float* pr1, const float* pr2,
                      const float* pr3, const float* text, const float* lsc,
                      char* ws) {
  __shared__ float red[256];
  int t = threadIdx.x, b = blockIdx.x;
  float* pmean = (float*)(ws + OFF_PMEAN);
  float* scal = (float*)(ws + OFF_SCAL);
  if (b < 32) {
    int l = b >> 3, chunk = b & 7;
    int C = 256 << l;
    const float* pr = (l == 0) ? pr0 : (l == 1) ? pr1 : (l == 2) ? pr2 : pr3;
    int cw = C >> 3;
    int c0 = chunk * cw;
    float s1 = 0.f, s2 = 0.f;
    for (int c = c0 + t; c < c0 + cw; c += 256) {
      float acc = 0.f;
      for (int r = 0; r < 64; ++r) acc += pr[r * C + c];
      float pm = acc * (1.0f / 64.0f);
      pmean[pm_off(l) + c] = pm;
      s1 += pm;
      s2 += pm * pm;
    }
    red[t] = s1;
    __syncthreads();
    for (int o = 128; o > 0; o >>= 1) {
      if (t < o) red[t] += red[t + o];
      __syncthreads();
    }
    float rs1 = red[0];
    __syncthreads();
    red[t] = s2;
    __syncthreads();
    for (int o = 128; o > 0; o >>= 1) {
      if (t < o) red[t] += red[t + o];
      __syncthreads();
    }
    if (t == 0) {
      scal[16 + l * 8 + chunk] = rs1;
      scal[48 + l * 8 + chunk] = red[0];
    }
  } else {
    float* tf = (float*)(ws + OFF_TEXT);
    for (int r = 0; r < 8; ++r) {
      float p = 0.f;
      for (int c = t; c < 512; c += 256) {
        float v = text[r * 512 + c];
        p += v * v;
      }
      red[t] = p;
      __syncthreads();
      for (int o = 128; o > 0; o >>= 1) {
        if (t < o) red[t] += red[t + o];
        __syncthreads();
      }
      float inv = 1.0f / fmaxf(sqrtf(red[0]), 1e-12f);
      __syncthreads();
      for (int c = t; c < 512; c += 256) tf[r * 512 + c] = text[r * 512 + c] * inv;
    }
    if (t == 0) {
      float s = fmaxf(lsc[0], 1e-4f);
      scal[8] = s * 0.04419417382415922f;  // 1/sqrt(512)
    }
  }
}

// ---------------- prep2: u/Gsum/Bsum partials + gwT (bf16, transposed) ----------------
struct P2Args {
  const float* W[4];
  const float* g[4];
  const float* beta[4];
  const float* bias[4];
  char* ws;
};

__global__ void prep2(P2Args A) {
  __shared__ unsigned short tile[64][72];
  __shared__ float r1[256], r2[256], r3[256];
  int t = threadIdx.x;
  int bid = blockIdx.x;
  int l = bid >> 5;
  int rem = bid & 31;
  int dchunk = rem >> 2, seg = rem & 3;
  int C = 256 << l, C2 = C * 2;
  int d0 = dchunk * 64;
  int dl = t & 63, jg = t >> 6;
  int d = d0 + dl;
  const float* W = A.W[l];
  const float* g = A.g[l];
  const float* beta = A.beta[l];
  const float* pmean = (const float*)(A.ws + OFF_PMEAN) + pm_off(l);
  unsigned short* gwT = (unsigned short*)(A.ws + gwt_off(l));
  float gs = 0.f, bs = 0.f, uu = 0.f;
  int span = C2 >> 2;      // C/2, multiple of 64
  int j0 = seg * span;
  bool top = (seg < 2);    // j < C: goes into gwT; j >= C: proto half -> u
  for (int jc = j0; jc < j0 + span; jc += 64) {
    for (int jj = jg; jj < 64; jj += 4) {
      int j = jc + jj;
      float w = W[(size_t)j * 512 + d];
      float gj = g[j];
      float gw = gj * w;
      gs += gw;
      bs += beta[j] * w;
      if (top) tile[jj][dl] = f2bf(gw);
      else uu += pmean[j - C] * gw;
    }
    if (top) {
      __syncthreads();
      int dr = t >> 2, q = t & 3;
      unsigned o[8];
#pragma unroll
      for (int i = 0; i < 8; ++i) {
        unsigned lo = tile[q * 16 + 2 * i][dr];
        unsigned hi = tile[q * 16 + 2 * i + 1][dr];
        o[i] = lo | (hi << 16);
      }
      uint4* dst = (uint4*)(gwT + (size_t)(d0 + dr) * C + jc + q * 16);
      dst[0] = make_uint4(o[0], o[1], o[2], o[3]);
      dst[1] = make_uint4(o[4], o[5], o[6], o[7]);
      __syncthreads();
    }
  }
  r1[t] = gs; r2[t] = bs; r3[t] = uu;
  __syncthreads();
  if (t < 64) {
    float G = 0.f, Bv = 0.f, U = 0.f;
    for (int k = 0; k < 4; ++k) {
      G += r1[k * 64 + t];
      Bv += r2[k * 64 + t];
      U += r3[k * 64 + t];
    }
    if (seg == 0) Bv += A.bias[l][d0 + t];
    int idx = (l * 4 + seg) * 512 + d0 + t;
    ((float*)(A.ws + OFF_U))[idx] = U;
    ((float*)(A.ws + OFF_GG))[idx] = G;
    ((float*)(A.ws + OFF_BB))[idx] = Bv;
  }
  if (seg == 0 && dchunk == 0 && t == 0) {
    float* scal = (float*)(A.ws + OFF_SCAL);
    float s1 = 0.f, s2 = 0.f;
    for (int k = 0; k < 8; ++k) { s1 += scal[16 + l * 8 + k]; s2 += scal[48 + l * 8 + k]; }
    scal[l] = s1;
    scal[4 + l] = s2;
  }
}

// ---------------- fused GEMM + LN-fold + relu + l2norm + text dots ----------------
struct GArgs {
  const float* pooled[4];
  const char* gwT[4];
  const float* Up;
  const float* Gp;
  const float* Bp;
  const float* scal;
  const float* textf;
  float* logits;
};

__global__ __launch_bounds__(256, 2) void gemm_fused(GArgs A) {
  // LDS layout (bytes):
  //  [0,32768)     Bs [n=512][k=32] bf16      | epilogue: wred[4][64][9] f32
  //  [32768,36864) As [r=64][k=32] bf16       | epilogue: red1/red2/rowM/rowIS
  //  [36864,53248) textL [8][512] f32
  //  [53248,55296) uL, [55296,57344) gL, [57344,59392) bL
  __shared__ __align__(16) char lds[59392];
  int t = threadIdx.x;
  int bid = blockIdx.x;
  int segb = bid >> 7;
  // pair heavy (l=3) blocks with light (l=0) in 2nd residency slot
  int l = (segb == 0) ? 3 : (segb == 1) ? 2 : (segb == 2) ? 0 : 1;
  int m0 = (bid & 127) * 64;
  int C = 256 << l;

  float* textL = (float*)(lds + 36864);
  float* uL = (float*)(lds + 53248);
  float* gL = (float*)(lds + 55296);
  float* bL = (float*)(lds + 57344);
  for (int i = t; i < 512; i += 256) {
    float su = 0.f, sg = 0.f, sb = 0.f;
    for (int s = 0; s < 4; ++s) {
      int idx = (l * 4 + s) * 512 + i;
      su += A.Up[idx]; sg += A.Gp[idx]; sb += A.Bp[idx];
    }
    uL[i] = su; gL[i] = sg; bL[i] = sb;
  }
  for (int i = t; i < 4096; i += 256) textL[i] = A.textf[i];

  int w = t >> 6, lane = t & 63;
  int quad = lane >> 4, lc = lane & 15;

  const char* bptr[8];
  char* bldsp[8];
  const char* gwTl = A.gwT[l];
#pragma unroll
  for (int c = 0; c < 8; ++c) {
    int linear = c * 256 + t;
    int n = linear >> 2, kq = linear & 3;
    bptr[c] = gwTl + (size_t)n * (size_t)(C * 2) + kq * 16;
    bldsp[c] = lds + c * 4096 + w * 1024;  // wave-uniform base; lane scatters *16B
  }
  int ar = t >> 2, aq = t & 3;
  const float* ap = A.pooled[l] + (size_t)(m0 + ar) * C + aq * 8;
  char* awp = lds + 32768 + ar * 64 + aq * 16;
  const char* aF = lds + 32768 + lc * 64 + quad * 16;
  const char* bF = lds + (w * 128 + lc) * 64 + quad * 16;

  f32x4 acc[4][8] = {};
  float sum = 0.f, sumsq = 0.f;

  for (int k0 = 0; k0 < C; k0 += 32) {
#pragma unroll
    for (int c = 0; c < 8; ++c) async_load16(bptr[c] + (size_t)k0 * 2, bldsp[c]);
    float4 x0 = *(const float4*)(ap + k0);
    float4 x1 = *(const float4*)(ap + k0 + 4);
    sum += x0.x + x0.y + x0.z + x0.w + x1.x + x1.y + x1.z + x1.w;
    sumsq = fmaf(x0.x, x0.x, sumsq); sumsq = fmaf(x0.y, x0.y, sumsq);
    sumsq = fmaf(x0.z, x0.z, sumsq); sumsq = fmaf(x0.w, x0.w, sumsq);
    sumsq = fmaf(x1.x, x1.x, sumsq); sumsq = fmaf(x1.y, x1.y, sumsq);
    sumsq = fmaf(x1.z, x1.z, sumsq); sumsq = fmaf(x1.w, x1.w, sumsq);
    uint4 pk;
    pk.x = pack2(x0.x, x0.y); pk.y = pack2(x0.z, x0.w);
    pk.z = pack2(x1.x, x1.y); pk.w = pack2(x1.z, x1.w);
    *(uint4*)awp = pk;
    __syncthreads();
    bf16x8 av[4];
#pragma unroll
    for (int rt = 0; rt < 4; ++rt) av[rt] = *(const bf16x8*)(aF + rt * 1024);
#pragma unroll
    for (int ct = 0; ct < 8; ++ct) {
      bf16x8 bv = *(const bf16x8*)(bF + ct * 1024);
#pragma unroll
      for (int rt = 0; rt < 4; ++rt)
        acc[rt][ct] = __builtin_amdgcn_mfma_f32_16x16x32_bf16(av[rt], bv, acc[rt][ct], 0, 0, 0);
    }
    __syncthreads();
  }

  // ---- row stats (mean / inv_std of the concat row) ----
  float* red1 = (float*)(lds + 32768);
  float* red2 = (float*)(lds + 33792);
  float* rowM = (float*)(lds + 34816);
  float* rowIS = (float*)(lds + 35072);
  red1[t] = sum; red2[t] = sumsq;
  __syncthreads();
  float sproto = A.scal[l], sqproto = A.scal[4 + l];
  float inv2C = 1.0f / (float)(2 * C);
  if (t < 64) {
    float s1 = red1[4 * t] + red1[4 * t + 1] + red1[4 * t + 2] + red1[4 * t + 3];
    float s2 = red2[4 * t] + red2[4 * t + 1] + red2[4 * t + 2] + red2[4 * t + 3];
    float mr = (s1 + sproto) * inv2C;
    float var = (s2 + sqproto) * inv2C - mr * mr;
    rowM[t] = mr;
    rowIS[t] = rsqrtf(var + 1e-5f);
  }
  __syncthreads();

  // ---- epilogue: h = relu(inv_s*(acc + u - m*Gsum) + Bsum); norm + 8 text dots ----
  float* wred = (float*)lds;
#pragma unroll
  for (int rt = 0; rt < 4; ++rt) {
    float np[4] = {0.f, 0.f, 0.f, 0.f};
    float dp[4][8] = {};
#pragma unroll
    for (int ct = 0; ct < 8; ++ct) {
      int d = w * 128 + ct * 16 + lc;
      float uu = uL[d], gg = gL[d], bb = bL[d];
      float tv[8];
#pragma unroll
      for (int k = 0; k < 8; ++k) tv[k] = textL[k * 512 + d];
      f32x4 a = acc[rt][ct];
#pragma unroll
      for (int reg = 0; reg < 4; ++reg) {
        int rloc = rt * 16 + quad * 4 + reg;
        float h = fmaf(a[reg] + uu - rowM[rloc] * gg, rowIS[rloc], bb);
        h = fmaxf(h, 0.f);
        np[reg] = fmaf(h, h, np[reg]);
#pragma unroll
        for (int k = 0; k < 8; ++k) dp[reg][k] = fmaf(h, tv[k], dp[reg][k]);
      }
    }
#pragma unroll
    for (int off = 1; off < 16; off <<= 1) {
#pragma unroll
      for (int reg = 0; reg < 4; ++reg) {
        np[reg] += __shfl_xor(np[reg], off);
#pragma unroll
        for (int k = 0; k < 8; ++k) dp[reg][k] += __shfl_xor(dp[reg][k], off);
      }
    }
    if (lc < 4) {
      int rloc = rt * 16 + quad * 4 + lc;
      float* dst = wred + (size_t)(w * 64 + rloc) * 9;
      dst[0] = np[lc];
#pragma unroll
      for (int k = 0; k < 8; ++k) dst[1 + k] = dp[lc][k];
    }
  }
  __syncthreads();
  if (t < 64) {
    float ns = 0.f;
    float dk[8] = {};
    for (int ww = 0; ww < 4; ++ww) {
      const float* src = wred + (size_t)(ww * 64 + t) * 9;
      ns += src[0];
#pragma unroll
      for (int k = 0; k < 8; ++k) dk[k] += src[1 + k];
    }
    float innorm = 1.0f / fmaxf(sqrtf(ns), 1e-12f);
    float sc = A.scal[8] * innorm;
    float* outp = A.logits + (size_t)(m0 + t) * 32;
#pragma unroll
    for (int k = 0; k < 8; ++k) outp[k * 4 + l] = dk[k] * sc;
  }
}

// ---------------- softmax over L=4 ----------------
__global__ void softmax_k(const float* logits, float* out) {
  int i = blockIdx.x * 256 + threadIdx.x;  // one (b,k) per thread
  float4 v = ((const float4*)logits)[i];
  float mx = fmaxf(fmaxf(v.x, v.y), fmaxf(v.z, v.w));
  float e0 = expf(v.x - mx), e1 = expf(v.y - mx);
  float e2 = expf(v.z - mx), e3 = expf(v.w - mx);
  float inv = 1.0f / (e0 + e1 + e2 + e3);
  ((float4*)out)[i] = make_float4(e0 * inv, e1 * inv, e2 * inv, e3 * inv);
}

extern "C" void kernel_launch(void* const* d_in, const int* in_sizes, int n_in,
                              void* d_out, int out_size, void* d_ws, size_t ws_size,
                              hipStream_t stream) {
  (void)n_in; (void)out_size; (void)ws_size;
  char* ws = (char*)d_ws;
  // setup_inputs() dict order: per-level groups of 6; fall back to signature order if sizes say so
  bool dict = (in_sizes[1] == 64 * 256);
  const float* pooled[4]; const float* proto[4]; const float* g[4];
  const float* beta[4];   const float* W[4];     const float* bias[4];
  for (int l = 0; l < 4; ++l) {
    if (dict) {
      pooled[l] = (const float*)d_in[6 * l + 0];
      proto[l]  = (const float*)d_in[6 * l + 1];
      g[l]      = (const float*)d_in[6 * l + 2];
      beta[l]   = (const float*)d_in[6 * l + 3];
      W[l]      = (const float*)d_in[6 * l + 4];
      bias[l]   = (const float*)d_in[6 * l + 5];
    } else {
      pooled[l] = (const float*)d_in[l];
      proto[l]  = (const float*)d_in[4 + l];
      g[l]      = (const float*)d_in[8 + l];
      beta[l]   = (const float*)d_in[12 + l];
      W[l]      = (const float*)d_in[16 + l];
      bias[l]   = (const float*)d_in[20 + l];
    }
  }
  const float* text = (const float*)d_in[24];
  const float* lsc = (const float*)d_in[25];

  prep1<<<33, 256, 0, stream>>>(proto[0], proto[1], proto[2], proto[3], text, lsc, ws);

  P2Args p2;
  for (int l = 0; l < 4; ++l) {
    p2.W[l] = W[l]; p2.g[l] = g[l]; p2.beta[l] = beta[l]; p2.bias[l] = bias[l];
  }
  p2.ws = ws;
  prep2<<<128, 256, 0, stream>>>(p2);

  GArgs ga;
  for (int l = 0; l < 4; ++l) {
    ga.pooled[l] = pooled[l];
    ga.gwT[l] = (const char*)(ws + gwt_off(l));
  }
  ga.Up = (const float*)(ws + OFF_U);
  ga.Gp = (const float*)(ws + OFF_GG);
  ga.Bp = (const float*)(ws + OFF_BB);
  ga.scal = (const float*)(ws + OFF_SCAL);
  ga.textf = (const float*)(ws + OFF_TEXT);
  ga.logits = (float*)(ws + OFF_LOGITS);
  gemm_fused<<<512, 256, 0, stream>>>(ga);

  softmax_k<<<256, 256, 0, stream>>>((const float*)(ws + OFF_LOGITS), (float*)d_out);
}

// Round 2
// 429.797 us; speedup vs baseline: 1.0987x; 1.0987x over previous
//
#include <hip/hip_runtime.h>
#include <stdint.h>

typedef __bf16 bf16x8 __attribute__((ext_vector_type(8)));
typedef float f32x4 __attribute__((ext_vector_type(4)));

// ---- workspace byte offsets ----
#define OFF_ABF   0u           // pooled as bf16, per level [8192][C]
#define OFF_GWT   62914560u    // (g*W)^T bf16 per level [512][C]
#define OFF_H     66846720u    // h bf16 per level [8192][512]
#define OFF_STAT  100401152u   // per (l,row): sum, sumsq  (4*8192*2 f32)
#define OFF_TEXT  100663296u   // 4096 f32 normalized text
#define OFF_U     100679680u   // 4 lvl * 4 seg * 512 f32
#define OFF_GG    100712448u
#define OFF_BB    100745216u
#define OFF_SCAL  100777984u   // [0..3] sproto, [4..7] sqproto, [8] scale
#define WS_TOTAL  100778496u

__host__ __device__ __forceinline__ size_t abf_off(int l) {
  return (size_t)4194304u * (size_t)((1u << l) - 1u);
}
__host__ __device__ __forceinline__ size_t gwt_off(int l) {
  return (size_t)262144u * (size_t)((1u << l) - 1u);
}

__device__ __forceinline__ unsigned short f2bf(float x) {
  return (unsigned short)((__float_as_uint(x) + 0x8000u) >> 16);
}
__device__ __forceinline__ unsigned pack2(float a, float b) {
  return ((__float_as_uint(a) + 0x8000u) >> 16) |
         ((__float_as_uint(b) + 0x8000u) & 0xffff0000u);
}
__device__ __forceinline__ void async_load16(const void* g, void* l) {
  __builtin_amdgcn_global_load_lds((const __attribute__((address_space(1))) void*)g,
                                   (__attribute__((address_space(3))) void*)l,
                                   16, 0, 0);
}

// ================= prep: A-convert+stats | gwT build | proto scal | text =================
struct PrepArgs {
  const float* pooled[4];
  const float* proto[4];
  const float* W[4];
  const float* g[4];
  const float* beta[4];
  const float* bias[4];
  const float* text;
  const float* lsc;
  char* ws;
};

__global__ void prep(PrepArgs A) {
  __shared__ unsigned short tile[64][72];   // gwT transpose staging
  __shared__ float r1[256], r2[256], r3[256];
  __shared__ float pm[1024];
  int t = threadIdx.x;
  int bid = blockIdx.x;

  if (bid < 512) {
    // ---- A convert + row stats: 128 blocks/level, 64 rows/block, heavy-first ----
    int l = 3 - (bid >> 7);
    int rblk = bid & 127;
    int C = 256 << l;
    int row = rblk * 64 + (t >> 2), q = t & 3;
    const float* P = A.pooled[l] + (size_t)row * C;
    char* Ab = A.ws + OFF_ABF + abf_off(l) + (size_t)row * C * 2;
    float s1 = 0.f, s2 = 0.f;
    int iters = C >> 4;
    for (int i = 0; i < iters; ++i) {
      int e = (i * 4 + q) * 4;
      float4 v = *(const float4*)(P + e);
      s1 += v.x + v.y + v.z + v.w;
      s2 = fmaf(v.x, v.x, s2); s2 = fmaf(v.y, v.y, s2);
      s2 = fmaf(v.z, v.z, s2); s2 = fmaf(v.w, v.w, s2);
      uint2 o;
      o.x = pack2(v.x, v.y);
      o.y = pack2(v.z, v.w);
      *(uint2*)(Ab + (size_t)e * 2) = o;
    }
    s1 += __shfl_xor(s1, 1); s1 += __shfl_xor(s1, 2);
    s2 += __shfl_xor(s2, 1); s2 += __shfl_xor(s2, 2);
    if (q == 0) {
      float* st = (float*)(A.ws + OFF_STAT) + (size_t)(l * 8192 + row) * 2;
      st[0] = s1; st[1] = s2;
    }
  } else if (bid < 640) {
    // ---- gwT build + u/G/B partials ----
    int id2 = bid - 512;
    int l = 3 - (id2 >> 5);
    int rem = id2 & 31;
    int dchunk = rem >> 2, seg = rem & 3;
    int C = 256 << l, C2 = C * 2;
    int d0 = dchunk * 64;
    int dl = t & 63, jg = t >> 6;
    int d = d0 + dl;
    const float* W = A.W[l];
    const float* g = A.g[l];
    const float* beta = A.beta[l];
    unsigned short* gwT = (unsigned short*)(A.ws + OFF_GWT + gwt_off(l));
    int span = C2 >> 2;   // C/2
    int j0 = seg * span;
    bool top = (seg < 2);
    if (!top) {
      // inline proto mean for this j-range
      const float* pr = A.proto[l];
      for (int c = t; c < span; c += 256) {
        const float* pp = pr + (j0 - C + c);
        float acc = 0.f;
        for (int r = 0; r < 64; ++r) acc += pp[(size_t)r * C];
        pm[c] = acc * (1.0f / 64.0f);
      }
      __syncthreads();
    }
    float gs = 0.f, bs = 0.f, uu = 0.f;
    for (int jc = j0; jc < j0 + span; jc += 64) {
      for (int jj = jg; jj < 64; jj += 4) {
        int j = jc + jj;
        float w = W[(size_t)j * 512 + d];
        float gw = g[j] * w;
        gs += gw;
        bs += beta[j] * w;
        if (top) tile[jj][dl] = f2bf(gw);
        else uu += pm[j - j0] * gw;
      }
      if (top) {
        __syncthreads();
        int dr = t >> 2, q4 = t & 3;
        unsigned o[8];
#pragma unroll
        for (int i = 0; i < 8; ++i) {
          unsigned lo = tile[q4 * 16 + 2 * i][dr];
          unsigned hi = tile[q4 * 16 + 2 * i + 1][dr];
          o[i] = lo | (hi << 16);
        }
        uint4* dst = (uint4*)(gwT + (size_t)(d0 + dr) * C + jc + q4 * 16);
        dst[0] = make_uint4(o[0], o[1], o[2], o[3]);
        dst[1] = make_uint4(o[4], o[5], o[6], o[7]);
        __syncthreads();
      }
    }
    r1[t] = gs; r2[t] = bs; r3[t] = uu;
    __syncthreads();
    if (t < 64) {
      float G = 0.f, Bv = 0.f, U = 0.f;
      for (int k = 0; k < 4; ++k) {
        G += r1[k * 64 + t];
        Bv += r2[k * 64 + t];
        U += r3[k * 64 + t];
      }
      if (seg == 0) Bv += A.bias[l][d0 + t];
      int idx = (l * 4 + seg) * 512 + d0 + t;
      ((float*)(A.ws + OFF_U))[idx] = U;
      ((float*)(A.ws + OFF_GG))[idx] = G;
      ((float*)(A.ws + OFF_BB))[idx] = Bv;
    }
  } else if (bid < 644) {
    // ---- per-level proto sums (sproto, sqproto) ----
    int l = bid - 640;
    int C = 256 << l;
    const float* pr = A.proto[l];
    float s1 = 0.f, s2 = 0.f;
    for (int c = t; c < C; c += 256) {
      float acc = 0.f;
      for (int r = 0; r < 64; ++r) acc += pr[(size_t)r * C + c];
      float pmv = acc * (1.0f / 64.0f);
      s1 += pmv;
      s2 = fmaf(pmv, pmv, s2);
    }
    r1[t] = s1; r2[t] = s2;
    __syncthreads();
    for (int o = 128; o > 0; o >>= 1) {
      if (t < o) { r1[t] += r1[t + o]; r2[t] += r2[t + o]; }
      __syncthreads();
    }
    if (t == 0) {
      float* scal = (float*)(A.ws + OFF_SCAL);
      scal[l] = r1[0];
      scal[4 + l] = r2[0];
    }
  } else {
    // ---- text l2norm + scale ----
    float* tf = (float*)(A.ws + OFF_TEXT);
    for (int r = 0; r < 8; ++r) {
      float p = 0.f;
      for (int c = t; c < 512; c += 256) {
        float v = A.text[r * 512 + c];
        p += v * v;
      }
      r1[t] = p;
      __syncthreads();
      for (int o = 128; o > 0; o >>= 1) {
        if (t < o) r1[t] += r1[t + o];
        __syncthreads();
      }
      float inv = 1.0f / fmaxf(sqrtf(r1[0]), 1e-12f);
      __syncthreads();
      for (int c = t; c < 512; c += 256) tf[r * 512 + c] = A.text[r * 512 + c] * inv;
    }
    if (t == 0) {
      float s = fmaxf(A.lsc[0], 1e-4f);
      ((float*)(A.ws + OFF_SCAL))[8] = s * 0.04419417382415922f;  // 1/sqrt(512)
    }
  }
}

// ================= gemm2: m97-shape 128x128 bf16 GEMM + LN-fold epilogue =================
__global__ __launch_bounds__(256, 3) void gemm2(char* ws) {
  __shared__ __align__(16) char lds[18944];
  int t = threadIdx.x, bid = blockIdx.x;
  int l = 3 - (bid >> 8);          // heavy levels first
  int rb = (bid >> 2) & 63, cb = bid & 3;
  int C = 256 << l;
  int m0 = rb * 128, n0 = cb * 128;

  float* uArr  = (float*)(lds + 16384);
  float* gArr  = (float*)(lds + 16896);
  float* bArr  = (float*)(lds + 17408);
  float* rowM  = (float*)(lds + 17920);
  float* rowIS = (float*)(lds + 18432);
  const float* scal = (const float*)(ws + OFF_SCAL);

  if (t < 128) {
    float su = 0.f, sg = 0.f, sb = 0.f;
    for (int s = 0; s < 4; ++s) {
      int idx = (l * 4 + s) * 512 + n0 + t;
      su += ((const float*)(ws + OFF_U))[idx];
      sg += ((const float*)(ws + OFF_GG))[idx];
      sb += ((const float*)(ws + OFF_BB))[idx];
    }
    uArr[t] = su; gArr[t] = sg; bArr[t] = sb;
  } else {
    int r = t - 128;
    const float* st = (const float*)(ws + OFF_STAT) + (size_t)(l * 8192 + m0 + r) * 2;
    float s1 = st[0], s2 = st[1];
    float inv2C = 1.0f / (float)(2 * C);
    float mr = (s1 + scal[l]) * inv2C;
    float var = (s2 + scal[4 + l]) * inv2C - mr * mr;
    rowM[r] = mr;
    rowIS[r] = rsqrtf(var + 1e-5f);
  }

  int w = t >> 6, lane = t & 63, quad = lane >> 4, lc = lane & 15;
  const char* Abf = ws + OFF_ABF + abf_off(l);
  const char* Bw  = ws + OFF_GWT + gwt_off(l);
  const char* aP[2]; const char* bP[2];
  char* aD[2]; char* bD[2];
#pragma unroll
  for (int i = 0; i < 2; ++i) {
    int li = i * 256 + t;
    int rr = li >> 2, kq = li & 3;
    aP[i] = Abf + ((size_t)(m0 + rr) * C + kq * 8) * 2;
    bP[i] = Bw  + ((size_t)(n0 + rr) * C + kq * 8) * 2;
    aD[i] = lds + i * 4096 + w * 1024;
    bD[i] = lds + 8192 + i * 4096 + w * 1024;
  }
  int wr = (w >> 1) * 64, wc = (w & 1) * 64;
  const char* aF = lds + (wr + lc) * 64 + quad * 16;
  const char* bF = lds + 8192 + (wc + lc) * 64 + quad * 16;

  f32x4 acc[4][4] = {};
  for (int k0 = 0; k0 < C; k0 += 32) {
    async_load16(aP[0], aD[0]); async_load16(aP[1], aD[1]);
    async_load16(bP[0], bD[0]); async_load16(bP[1], bD[1]);
    aP[0] += 64; aP[1] += 64; bP[0] += 64; bP[1] += 64;
    __syncthreads();
    bf16x8 av[4];
#pragma unroll
    for (int rt = 0; rt < 4; ++rt) av[rt] = *(const bf16x8*)(aF + rt * 1024);
#pragma unroll
    for (int ct = 0; ct < 4; ++ct) {
      bf16x8 bv = *(const bf16x8*)(bF + ct * 1024);
#pragma unroll
      for (int rt = 0; rt < 4; ++rt)
        acc[rt][ct] = __builtin_amdgcn_mfma_f32_16x16x32_bf16(av[rt], bv, acc[rt][ct], 0, 0, 0);
    }
    __syncthreads();
  }

  // epilogue: h = relu((acc + u - m*G)*invs + B) -> bf16 store
  char* Hl = ws + OFF_H + (size_t)l * 8388608;
#pragma unroll
  for (int rt = 0; rt < 4; ++rt) {
#pragma unroll
    for (int ct = 0; ct < 4; ++ct) {
      int nl = wc + ct * 16 + lc;
      float uu = uArr[nl], gg = gArr[nl], bb = bArr[nl];
      f32x4 a = acc[rt][ct];
#pragma unroll
      for (int reg = 0; reg < 4; ++reg) {
        int ml = wr + rt * 16 + quad * 4 + reg;
        float h = fmaf(a[reg] + uu - rowM[ml] * gg, rowIS[ml], bb);
        h = fmaxf(h, 0.f);
        float hp = __shfl_xor(h, 1);
        if (!(lc & 1)) {
          unsigned pkv = pack2(h, hp);
          *(unsigned*)(Hl + ((size_t)(m0 + ml) * 512 + n0 + nl) * 2) = pkv;
        }
      }
    }
  }
}

// ================= postK: l2norm + text dots + softmax =================
__global__ void postK(const char* ws, float* out) {
  __shared__ float textL[4096];
  int t = threadIdx.x, b = blockIdx.x;
  const float* tf = (const float*)(ws + OFF_TEXT);
  for (int i = t; i < 4096; i += 256) textL[i] = tf[i];
  __syncthreads();
  float scale = ((const float*)(ws + OFF_SCAL))[8];
  int row = b * 64 + (t >> 2), q = t & 3;
  float lg[4][8];
#pragma unroll
  for (int l = 0; l < 4; ++l) {
    const uint4* hp = (const uint4*)(ws + OFF_H + (size_t)l * 8388608 +
                                     ((size_t)row * 512 + q * 128) * 2);
    float np = 0.f;
    float dp[8] = {};
    for (int ch = 0; ch < 16; ++ch) {
      uint4 u = hp[ch];
      int d0 = q * 128 + ch * 8;
      unsigned uw[4] = {u.x, u.y, u.z, u.w};
#pragma unroll
      for (int p = 0; p < 4; ++p) {
        float v0 = __uint_as_float(uw[p] << 16);
        float v1 = __uint_as_float(uw[p] & 0xffff0000u);
        int dd = d0 + p * 2;
        np = fmaf(v0, v0, np);
        np = fmaf(v1, v1, np);
#pragma unroll
        for (int k = 0; k < 8; ++k) {
          dp[k] = fmaf(v0, textL[k * 512 + dd], dp[k]);
          dp[k] = fmaf(v1, textL[k * 512 + dd + 1], dp[k]);
        }
      }
    }
    np += __shfl_xor(np, 1); np += __shfl_xor(np, 2);
#pragma unroll
    for (int k = 0; k < 8; ++k) {
      dp[k] += __shfl_xor(dp[k], 1);
      dp[k] += __shfl_xor(dp[k], 2);
    }
    float innorm = scale / fmaxf(sqrtf(np), 1e-12f);
#pragma unroll
    for (int k = 0; k < 8; ++k) lg[l][k] = dp[k] * innorm;
  }
  if (q == 0) {
    float4* op = (float4*)out + (size_t)row * 8;
#pragma unroll
    for (int k = 0; k < 8; ++k) {
      float a = lg[0][k], b2 = lg[1][k], c = lg[2][k], d = lg[3][k];
      float mx = fmaxf(fmaxf(a, b2), fmaxf(c, d));
      float e0 = __expf(a - mx), e1 = __expf(b2 - mx);
      float e2 = __expf(c - mx), e3 = __expf(d - mx);
      float inv = 1.0f / (e0 + e1 + e2 + e3);
      op[k] = make_float4(e0 * inv, e1 * inv, e2 * inv, e3 * inv);
    }
  }
}

extern "C" void kernel_launch(void* const* d_in, const int* in_sizes, int n_in,
                              void* d_out, int out_size, void* d_ws, size_t ws_size,
                              hipStream_t stream) {
  (void)n_in; (void)out_size;
  if (ws_size < (size_t)WS_TOTAL) return;  // loud failure: output stays poisoned
  char* ws = (char*)d_ws;
  bool dict = (in_sizes[1] == 64 * 256);
  PrepArgs pa;
  for (int l = 0; l < 4; ++l) {
    if (dict) {
      pa.pooled[l] = (const float*)d_in[6 * l + 0];
      pa.proto[l]  = (const float*)d_in[6 * l + 1];
      pa.g[l]      = (const float*)d_in[6 * l + 2];
      pa.beta[l]   = (const float*)d_in[6 * l + 3];
      pa.W[l]      = (const float*)d_in[6 * l + 4];
      pa.bias[l]   = (const float*)d_in[6 * l + 5];
    } else {
      pa.pooled[l] = (const float*)d_in[l];
      pa.proto[l]  = (const float*)d_in[4 + l];
      pa.g[l]      = (const float*)d_in[8 + l];
      pa.beta[l]   = (const float*)d_in[12 + l];
      pa.W[l]      = (const float*)d_in[16 + l];
      pa.bias[l]   = (const float*)d_in[20 + l];
    }
  }
  pa.text = (const float*)d_in[24];
  pa.lsc = (const float*)d_in[25];
  pa.ws = ws;

  prep<<<645, 256, 0, stream>>>(pa);
  gemm2<<<1024, 256, 0, stream>>>(ws);
  postK<<<128, 256, 0, stream>>>(ws, (float*)d_out);
}

// Round 3
// 383.764 us; speedup vs baseline: 1.2305x; 1.1200x over previous
//
#include <hip/hip_runtime.h>
#include <stdint.h>

typedef __bf16 bf16x8 __attribute__((ext_vector_type(8)));
typedef float f32x4 __attribute__((ext_vector_type(4)));

// ---- workspace byte offsets ----
#define OFF_ABF   0u           // pooled as bf16, per level [8192][C]
#define OFF_GWT   62914560u    // (g*W)^T bf16 per level [512][C]
#define OFF_H     66846720u    // h bf16 per level [8192][512]
#define OFF_STAT  100401152u   // per (l,row): sum, sumsq  (4*8192*2 f32)
#define OFF_TEXT  100663296u   // 4096 f32 normalized text
#define OFF_U     100679680u   // 4 lvl * 4 seg * 512 f32
#define OFF_GG    100712448u
#define OFF_BB    100745216u
#define OFF_SCAL  100777984u   // [0..3] sproto, [4..7] sqproto, [8] scale
#define WS_TOTAL  100778496u

__host__ __device__ __forceinline__ size_t abf_off(int l) {
  return (size_t)4194304u * (size_t)((1u << l) - 1u);
}
__host__ __device__ __forceinline__ size_t gwt_off(int l) {
  return (size_t)262144u * (size_t)((1u << l) - 1u);
}

__device__ __forceinline__ unsigned short f2bf(float x) {
  return (unsigned short)((__float_as_uint(x) + 0x8000u) >> 16);
}
__device__ __forceinline__ unsigned pack2(float a, float b) {
  return ((__float_as_uint(a) + 0x8000u) >> 16) |
         ((__float_as_uint(b) + 0x8000u) & 0xffff0000u);
}
__device__ __forceinline__ void async_load16(const void* g, void* l) {
  __builtin_amdgcn_global_load_lds((const __attribute__((address_space(1))) void*)g,
                                   (__attribute__((address_space(3))) void*)l,
                                   16, 0, 0);
}

// ================= prep =================
struct PrepArgs {
  const float* pooled[4];
  const float* proto[4];
  const float* W[4];
  const float* g[4];
  const float* beta[4];
  const float* bias[4];
  const float* text;
  const float* lsc;
  char* ws;
};

// A-convert: one wave handles 2 rows; N4 independent float4 loads in flight per row.
template <int N4>
__device__ __forceinline__ void aconv(const float* Pl, char* Ab, float* st,
                                      int C, int rowBase, int wave, int lane) {
  for (int rr = 0; rr < 2; ++rr) {
    int row = rowBase + wave * 2 + rr;
    const float4* P = (const float4*)(Pl + (size_t)row * C);
    uint2* D = (uint2*)(Ab + (size_t)row * C * 2);
    float4 v[N4];
#pragma unroll
    for (int i = 0; i < N4; ++i) v[i] = P[lane + 64 * i];
    float s1 = 0.f, s2 = 0.f;
#pragma unroll
    for (int i = 0; i < N4; ++i) {
      s1 += v[i].x + v[i].y + v[i].z + v[i].w;
      s2 = fmaf(v[i].x, v[i].x, s2); s2 = fmaf(v[i].y, v[i].y, s2);
      s2 = fmaf(v[i].z, v[i].z, s2); s2 = fmaf(v[i].w, v[i].w, s2);
      uint2 o;
      o.x = pack2(v[i].x, v[i].y);
      o.y = pack2(v[i].z, v[i].w);
      D[lane + 64 * i] = o;
    }
#pragma unroll
    for (int off = 1; off < 64; off <<= 1) {
      s1 += __shfl_xor(s1, off);
      s2 += __shfl_xor(s2, off);
    }
    if (lane == 0) {
      st[(size_t)row * 2] = s1;
      st[(size_t)row * 2 + 1] = s2;
    }
  }
}

__global__ void prep(PrepArgs A) {
  __shared__ unsigned short tile[64][72];
  __shared__ float r1[256], r2[256], r3[256];
  __shared__ float pm[1024];
  __shared__ float gsh[1024], bsh[1024];
  int t = threadIdx.x;
  int bid = blockIdx.x;

  if (bid < 128) {
    // ---- gwT build + u/G/B partials ----
    int l = 3 - (bid >> 5);
    int rem = bid & 31;
    int dchunk = rem >> 2, seg = rem & 3;
    int C = 256 << l, C2 = C * 2;
    int d0 = dchunk * 64;
    int dl = t & 63, jg = t >> 6;
    int d = d0 + dl;
    const float* W = A.W[l];
    const float* g = A.g[l];
    const float* beta = A.beta[l];
    unsigned short* gwT = (unsigned short*)(A.ws + OFF_GWT + gwt_off(l));
    int span = C2 >> 2;   // C/2
    int j0 = seg * span;
    bool top = (seg < 2);
    for (int i = t; i < span; i += 256) {
      gsh[i] = g[j0 + i];
      bsh[i] = beta[j0 + i];
    }
    if (!top) {
      const float* pr = A.proto[l];
      for (int c = t; c < span; c += 256) {
        const float* pp = pr + (j0 - C + c);
        float acc = 0.f;
#pragma unroll
        for (int r = 0; r < 64; ++r) acc += pp[(size_t)r * C];
        pm[c] = acc * (1.0f / 64.0f);
      }
    }
    __syncthreads();
    float gs = 0.f, bs = 0.f, uu = 0.f;
    for (int jc = j0; jc < j0 + span; jc += 64) {
      int jb = jc - j0;
      float wv[16];
#pragma unroll
      for (int u = 0; u < 16; ++u)
        wv[u] = W[(size_t)(jc + jg + 4 * u) * 512 + d];
#pragma unroll
      for (int u = 0; u < 16; ++u) {
        int jj = jg + 4 * u;
        float gw = gsh[jb + jj] * wv[u];
        gs += gw;
        bs = fmaf(bsh[jb + jj], wv[u], bs);
        if (top) tile[jj][dl] = f2bf(gw);
        else uu = fmaf(pm[jb + jj], gw, uu);
      }
      if (top) {
        __syncthreads();
        int dr = t >> 2, q4 = t & 3;
        unsigned o[8];
#pragma unroll
        for (int i = 0; i < 8; ++i) {
          unsigned lo = tile[q4 * 16 + 2 * i][dr];
          unsigned hi = tile[q4 * 16 + 2 * i + 1][dr];
          o[i] = lo | (hi << 16);
        }
        uint4* dst = (uint4*)(gwT + (size_t)(d0 + dr) * C + jc + q4 * 16);
        dst[0] = make_uint4(o[0], o[1], o[2], o[3]);
        dst[1] = make_uint4(o[4], o[5], o[6], o[7]);
        __syncthreads();
      }
    }
    r1[t] = gs; r2[t] = bs; r3[t] = uu;
    __syncthreads();
    if (t < 64) {
      float G = 0.f, Bv = 0.f, U = 0.f;
      for (int k = 0; k < 4; ++k) {
        G += r1[k * 64 + t];
        Bv += r2[k * 64 + t];
        U += r3[k * 64 + t];
      }
      if (seg == 0) Bv += A.bias[l][d0 + t];
      int idx = (l * 4 + seg) * 512 + d0 + t;
      ((float*)(A.ws + OFF_U))[idx] = U;
      ((float*)(A.ws + OFF_GG))[idx] = G;
      ((float*)(A.ws + OFF_BB))[idx] = Bv;
    }
  } else if (bid < 132) {
    // ---- per-level proto sums (sproto, sqproto) ----
    int l = bid - 128;
    int C = 256 << l;
    const float* pr = A.proto[l];
    float s1 = 0.f, s2 = 0.f;
    for (int c = t; c < C; c += 256) {
      const float* pp = pr + c;
      float acc = 0.f;
#pragma unroll
      for (int r = 0; r < 64; ++r) acc += pp[(size_t)r * C];
      float pmv = acc * (1.0f / 64.0f);
      s1 += pmv;
      s2 = fmaf(pmv, pmv, s2);
    }
    r1[t] = s1; r2[t] = s2;
    __syncthreads();
    for (int o = 128; o > 0; o >>= 1) {
      if (t < o) { r1[t] += r1[t + o]; r2[t] += r2[t + o]; }
      __syncthreads();
    }
    if (t == 0) {
      float* scal = (float*)(A.ws + OFF_SCAL);
      scal[l] = r1[0];
      scal[4 + l] = r2[0];
    }
  } else if (bid == 132) {
    // ---- text l2norm + scale ----
    float* tf = (float*)(A.ws + OFF_TEXT);
    for (int r = 0; r < 8; ++r) {
      float p = 0.f;
      for (int c = t; c < 512; c += 256) {
        float v = A.text[r * 512 + c];
        p += v * v;
      }
      r1[t] = p;
      __syncthreads();
      for (int o = 128; o > 0; o >>= 1) {
        if (t < o) r1[t] += r1[t + o];
        __syncthreads();
      }
      float inv = 1.0f / fmaxf(sqrtf(r1[0]), 1e-12f);
      __syncthreads();
      for (int c = t; c < 512; c += 256) tf[r * 512 + c] = A.text[r * 512 + c] * inv;
    }
    if (t == 0) {
      float s = fmaxf(A.lsc[0], 1e-4f);
      ((float*)(A.ws + OFF_SCAL))[8] = s * 0.04419417382415922f;  // 1/sqrt(512)
    }
  } else {
    // ---- A convert + row stats: 1024 blocks/level, 8 rows/block ----
    int ab = bid - 133;
    int l = 3 - (ab >> 10);
    int rblk = ab & 1023;
    int C = 256 << l;
    int rowBase = rblk * 8;
    int wave = t >> 6, lane = t & 63;
    const float* Pl = A.pooled[l];
    char* Ab = A.ws + OFF_ABF + abf_off(l);
    float* st = (float*)(A.ws + OFF_STAT) + (size_t)l * 8192 * 2;
    if (l == 3)      aconv<8>(Pl, Ab, st, C, rowBase, wave, lane);
    else if (l == 2) aconv<4>(Pl, Ab, st, C, rowBase, wave, lane);
    else if (l == 1) aconv<2>(Pl, Ab, st, C, rowBase, wave, lane);
    else             aconv<1>(Pl, Ab, st, C, rowBase, wave, lane);
  }
}

// ================= gemm2: m97-shape 128x128 bf16 GEMM + LN-fold epilogue =================
__global__ __launch_bounds__(256, 3) void gemm2(char* ws) {
  __shared__ __align__(16) char lds[18944];
  int t = threadIdx.x, bid = blockIdx.x;
  int l = 3 - (bid >> 8);          // heavy levels first
  int rb = (bid >> 2) & 63, cb = bid & 3;
  int C = 256 << l;
  int m0 = rb * 128, n0 = cb * 128;

  float* uArr  = (float*)(lds + 16384);
  float* gArr  = (float*)(lds + 16896);
  float* bArr  = (float*)(lds + 17408);
  float* rowM  = (float*)(lds + 17920);
  float* rowIS = (float*)(lds + 18432);
  const float* scal = (const float*)(ws + OFF_SCAL);

  if (t < 128) {
    float su = 0.f, sg = 0.f, sb = 0.f;
    for (int s = 0; s < 4; ++s) {
      int idx = (l * 4 + s) * 512 + n0 + t;
      su += ((const float*)(ws + OFF_U))[idx];
      sg += ((const float*)(ws + OFF_GG))[idx];
      sb += ((const float*)(ws + OFF_BB))[idx];
    }
    uArr[t] = su; gArr[t] = sg; bArr[t] = sb;
  } else {
    int r = t - 128;
    const float* st = (const float*)(ws + OFF_STAT) + (size_t)(l * 8192 + m0 + r) * 2;
    float s1 = st[0], s2 = st[1];
    float inv2C = 1.0f / (float)(2 * C);
    float mr = (s1 + scal[l]) * inv2C;
    float var = (s2 + scal[4 + l]) * inv2C - mr * mr;
    rowM[r] = mr;
    rowIS[r] = rsqrtf(var + 1e-5f);
  }

  int w = t >> 6, lane = t & 63, quad = lane >> 4, lc = lane & 15;
  const char* Abf = ws + OFF_ABF + abf_off(l);
  const char* Bw  = ws + OFF_GWT + gwt_off(l);
  const char* aP[2]; const char* bP[2];
  char* aD[2]; char* bD[2];
#pragma unroll
  for (int i = 0; i < 2; ++i) {
    int li = i * 256 + t;
    int rr = li >> 2, kq = li & 3;
    aP[i] = Abf + ((size_t)(m0 + rr) * C + kq * 8) * 2;
    bP[i] = Bw  + ((size_t)(n0 + rr) * C + kq * 8) * 2;
    aD[i] = lds + i * 4096 + w * 1024;
    bD[i] = lds + 8192 + i * 4096 + w * 1024;
  }
  int wr = (w >> 1) * 64, wc = (w & 1) * 64;
  const char* aF = lds + (wr + lc) * 64 + quad * 16;
  const char* bF = lds + 8192 + (wc + lc) * 64 + quad * 16;

  f32x4 acc[4][4] = {};
  for (int k0 = 0; k0 < C; k0 += 32) {
    async_load16(aP[0], aD[0]); async_load16(aP[1], aD[1]);
    async_load16(bP[0], bD[0]); async_load16(bP[1], bD[1]);
    aP[0] += 64; aP[1] += 64; bP[0] += 64; bP[1] += 64;
    __syncthreads();
    bf16x8 av[4];
#pragma unroll
    for (int rt = 0; rt < 4; ++rt) av[rt] = *(const bf16x8*)(aF + rt * 1024);
#pragma unroll
    for (int ct = 0; ct < 4; ++ct) {
      bf16x8 bv = *(const bf16x8*)(bF + ct * 1024);
#pragma unroll
      for (int rt = 0; rt < 4; ++rt)
        acc[rt][ct] = __builtin_amdgcn_mfma_f32_16x16x32_bf16(av[rt], bv, acc[rt][ct], 0, 0, 0);
    }
    __syncthreads();
  }

  // epilogue: h = relu((acc + u - m*G)*invs + B) -> bf16 store
  char* Hl = ws + OFF_H + (size_t)l * 8388608;
#pragma unroll
  for (int rt = 0; rt < 4; ++rt) {
#pragma unroll
    for (int ct = 0; ct < 4; ++ct) {
      int nl = wc + ct * 16 + lc;
      float uu = uArr[nl], gg = gArr[nl], bb = bArr[nl];
      f32x4 a = acc[rt][ct];
#pragma unroll
      for (int reg = 0; reg < 4; ++reg) {
        int ml = wr + rt * 16 + quad * 4 + reg;
        float h = fmaf(a[reg] + uu - rowM[ml] * gg, rowIS[ml], bb);
        h = fmaxf(h, 0.f);
        float hp = __shfl_xor(h, 1);
        if (!(lc & 1)) {
          unsigned pkv = pack2(h, hp);
          *(unsigned*)(Hl + ((size_t)(m0 + ml) * 512 + n0 + nl) * 2) = pkv;
        }
      }
    }
  }
}

// ================= postK: l2norm + text dots + softmax =================
__global__ void postK(const char* ws, float* out) {
  __shared__ float textL[4096];
  int t = threadIdx.x, b = blockIdx.x;
  const float* tf = (const float*)(ws + OFF_TEXT);
  for (int i = t; i < 4096; i += 256) textL[i] = tf[i];
  __syncthreads();
  float scale = ((const float*)(ws + OFF_SCAL))[8];
  int row = b * 64 + (t >> 2), q = t & 3;
  float lg[4][8];
#pragma unroll
  for (int l = 0; l < 4; ++l) {
    const uint4* hp = (const uint4*)(ws + OFF_H + (size_t)l * 8388608 +
                                     ((size_t)row * 512 + q * 128) * 2);
    float np = 0.f;
    float dp[8] = {};
    for (int ch = 0; ch < 16; ++ch) {
      uint4 u = hp[ch];
      int d0 = q * 128 + ch * 8;
      unsigned uw[4] = {u.x, u.y, u.z, u.w};
#pragma unroll
      for (int p = 0; p < 4; ++p) {
        float v0 = __uint_as_float(uw[p] << 16);
        float v1 = __uint_as_float(uw[p] & 0xffff0000u);
        int dd = d0 + p * 2;
        np = fmaf(v0, v0, np);
        np = fmaf(v1, v1, np);
#pragma unroll
        for (int k = 0; k < 8; ++k) {
          dp[k] = fmaf(v0, textL[k * 512 + dd], dp[k]);
          dp[k] = fmaf(v1, textL[k * 512 + dd + 1], dp[k]);
        }
      }
    }
    np += __shfl_xor(np, 1); np += __shfl_xor(np, 2);
#pragma unroll
    for (int k = 0; k < 8; ++k) {
      dp[k] += __shfl_xor(dp[k], 1);
      dp[k] += __shfl_xor(dp[k], 2);
    }
    float innorm = scale / fmaxf(sqrtf(np), 1e-12f);
#pragma unroll
    for (int k = 0; k < 8; ++k) lg[l][k] = dp[k] * innorm;
  }
  if (q == 0) {
    float4* op = (float4*)out + (size_t)row * 8;
#pragma unroll
    for (int k = 0; k < 8; ++k) {
      float a = lg[0][k], b2 = lg[1][k], c = lg[2][k], d = lg[3][k];
      float mx = fmaxf(fmaxf(a, b2), fmaxf(c, d));
      float e0 = __expf(a - mx), e1 = __expf(b2 - mx);
      float e2 = __expf(c - mx), e3 = __expf(d - mx);
      float inv = 1.0f / (e0 + e1 + e2 + e3);
      op[k] = make_float4(e0 * inv, e1 * inv, e2 * inv, e3 * inv);
    }
  }
}

extern "C" void kernel_launch(void* const* d_in, const int* in_sizes, int n_in,
                              void* d_out, int out_size, void* d_ws, size_t ws_size,
                              hipStream_t stream) {
  (void)n_in; (void)out_size;
  if (ws_size < (size_t)WS_TOTAL) return;  // loud failure: output stays poisoned
  char* ws = (char*)d_ws;
  bool dict = (in_sizes[1] == 64 * 256);
  PrepArgs pa;
  for (int l = 0; l < 4; ++l) {
    if (dict) {
      pa.pooled[l] = (const float*)d_in[6 * l + 0];
      pa.proto[l]  = (const float*)d_in[6 * l + 1];
      pa.g[l]      = (const float*)d_in[6 * l + 2];
      pa.beta[l]   = (const float*)d_in[6 * l + 3];
      pa.W[l]      = (const float*)d_in[6 * l + 4];
      pa.bias[l]   = (const float*)d_in[6 * l + 5];
    } else {
      pa.pooled[l] = (const float*)d_in[l];
      pa.proto[l]  = (const float*)d_in[4 + l];
      pa.g[l]      = (const float*)d_in[8 + l];
      pa.beta[l]   = (const float*)d_in[12 + l];
      pa.W[l]      = (const float*)d_in[16 + l];
      pa.bias[l]   = (const float*)d_in[20 + l];
    }
  }
  pa.text = (const float*)d_in[24];
  pa.lsc = (const float*)d_in[25];
  pa.ws = ws;

  prep<<<4229, 256, 0, stream>>>(pa);
  gemm2<<<1024, 256, 0, stream>>>(ws);
  postK<<<128, 256, 0, stream>>>(ws, (float*)d_out);
}

// Round 4
// 359.943 us; speedup vs baseline: 1.3120x; 1.0662x over previous
//
#include <hip/hip_runtime.h>
#include <stdint.h>

typedef __bf16 bf16x8 __attribute__((ext_vector_type(8)));
typedef float f32x4 __attribute__((ext_vector_type(4)));

// ---- workspace byte offsets ----
#define OFF_ABF   0u           // pooled as bf16, per level [8192][C]
#define OFF_GWT   62914560u    // (g*W)^T bf16 per level [512][C]
#define OFF_H     66846720u    // h bf16 per level [8192][512]
#define OFF_STAT  100401152u   // per (l,row): sum, sumsq  (4*8192*2 f32)
#define OFF_TEXT  100663296u   // 4096 f32 normalized text
#define OFF_U     100679680u   // 4 lvl * 4 seg * 512 f32
#define OFF_GG    100712448u
#define OFF_BB    100745216u
#define OFF_SCAL  100777984u   // [0..3] sproto, [4..7] sqproto, [8] scale
#define WS_TOTAL  100778496u

__host__ __device__ __forceinline__ size_t abf_off(int l) {
  return (size_t)4194304u * (size_t)((1u << l) - 1u);
}
__host__ __device__ __forceinline__ size_t gwt_off(int l) {
  return (size_t)262144u * (size_t)((1u << l) - 1u);
}

__device__ __forceinline__ unsigned short f2bf(float x) {
  return (unsigned short)((__float_as_uint(x) + 0x8000u) >> 16);
}
__device__ __forceinline__ unsigned pack2(float a, float b) {
  return ((__float_as_uint(a) + 0x8000u) >> 16) |
         ((__float_as_uint(b) + 0x8000u) & 0xffff0000u);
}
__device__ __forceinline__ void async_load16(const void* g, void* l) {
  __builtin_amdgcn_global_load_lds((const __attribute__((address_space(1))) void*)g,
                                   (__attribute__((address_space(3))) void*)l,
                                   16, 0, 0);
}

// ================= prep =================
struct PrepArgs {
  const float* pooled[4];
  const float* proto[4];
  const float* W[4];
  const float* g[4];
  const float* beta[4];
  const float* bias[4];
  const float* text;
  const float* lsc;
  char* ws;
};

// A-convert: one wave handles R rows; R*N4 == 8 independent float4 loads
// (8 KB/wave) in flight for every level.
template <int N4, int R>
__device__ __forceinline__ void aconvN(const float* Pl, char* Ab, float* st,
                                       int C, int rowBase, int lane) {
  float4 v[R][N4];
#pragma unroll
  for (int r = 0; r < R; ++r) {
    const float4* P = (const float4*)(Pl + (size_t)(rowBase + r) * C);
#pragma unroll
    for (int i = 0; i < N4; ++i) v[r][i] = P[lane + 64 * i];
  }
#pragma unroll
  for (int r = 0; r < R; ++r) {
    uint2* D = (uint2*)(Ab + (size_t)(rowBase + r) * C * 2);
    float s1 = 0.f, s2 = 0.f;
#pragma unroll
    for (int i = 0; i < N4; ++i) {
      float4 x = v[r][i];
      s1 += x.x + x.y + x.z + x.w;
      s2 = fmaf(x.x, x.x, s2); s2 = fmaf(x.y, x.y, s2);
      s2 = fmaf(x.z, x.z, s2); s2 = fmaf(x.w, x.w, s2);
      uint2 o;
      o.x = pack2(x.x, x.y);
      o.y = pack2(x.z, x.w);
      D[lane + 64 * i] = o;
    }
#pragma unroll
    for (int off = 1; off < 64; off <<= 1) {
      s1 += __shfl_xor(s1, off);
      s2 += __shfl_xor(s2, off);
    }
    if (lane == 0) {
      st[(size_t)(rowBase + r) * 2] = s1;
      st[(size_t)(rowBase + r) * 2 + 1] = s2;
    }
  }
}

__global__ __launch_bounds__(256, 6) void prep(PrepArgs A) {
  extern __shared__ char smem[];
  int t = threadIdx.x;
  int bid = blockIdx.x;

  if (bid >= 133) {
    // ---- A convert + row stats: zero-LDS streaming blocks ----
    int ab = bid - 133;
    int wave = t >> 6, lane = t & 63;
    int l, rowBase;
    if (ab < 2048)      { l = 3; rowBase = ab * 4 + wave; }
    else if (ab < 3072) { l = 2; rowBase = (ab - 2048) * 8 + wave * 2; }
    else if (ab < 3584) { l = 1; rowBase = (ab - 3072) * 16 + wave * 4; }
    else                { l = 0; rowBase = (ab - 3584) * 32 + wave * 8; }
    int C = 256 << l;
    const float* Pl = A.pooled[l];
    char* Ab = A.ws + OFF_ABF + abf_off(l);
    float* st = (float*)(A.ws + OFF_STAT) + (size_t)l * 8192 * 2;
    if (l == 3)      aconvN<8, 1>(Pl, Ab, st, C, rowBase, lane);
    else if (l == 2) aconvN<4, 2>(Pl, Ab, st, C, rowBase, lane);
    else if (l == 1) aconvN<2, 4>(Pl, Ab, st, C, rowBase, lane);
    else             aconvN<1, 8>(Pl, Ab, st, C, rowBase, lane);
    return;
  }

  // carved dynamic LDS (only misc blocks use it)
  unsigned short (*tile)[72] = (unsigned short (*)[72])smem;  // 9216 B
  float* r1 = (float*)(smem + 9216);
  float* r2 = r1 + 256;
  float* r3 = r2 + 256;                                        // -> 12288
  float* pm = (float*)(smem + 12288);                          // -> 16384
  float* gsh = (float*)(smem + 16384);                         // -> 20480
  float* bsh = (float*)(smem + 20480);                         // -> 24576

  if (bid < 128) {
    // ---- gwT build + u/G/B partials ----
    int l = 3 - (bid >> 5);
    int rem = bid & 31;
    int dchunk = rem >> 2, seg = rem & 3;
    int C = 256 << l, C2 = C * 2;
    int d0 = dchunk * 64;
    int dl = t & 63, jg = t >> 6;
    int d = d0 + dl;
    const float* W = A.W[l];
    const float* g = A.g[l];
    const float* beta = A.beta[l];
    unsigned short* gwT = (unsigned short*)(A.ws + OFF_GWT + gwt_off(l));
    int span = C2 >> 2;   // C/2
    int j0 = seg * span;
    bool top = (seg < 2);
    for (int i = t; i < span; i += 256) {
      gsh[i] = g[j0 + i];
      bsh[i] = beta[j0 + i];
    }
    if (!top) {
      const float* pr = A.proto[l];
      for (int c = t; c < span; c += 256) {
        const float* pp = pr + (j0 - C + c);
        float acc = 0.f;
#pragma unroll
        for (int r = 0; r < 64; ++r) acc += pp[(size_t)r * C];
        pm[c] = acc * (1.0f / 64.0f);
      }
    }
    __syncthreads();
    float gs = 0.f, bs = 0.f, uu = 0.f;
    for (int jc = j0; jc < j0 + span; jc += 64) {
      int jb = jc - j0;
      float wv[16];
#pragma unroll
      for (int u = 0; u < 16; ++u)
        wv[u] = W[(size_t)(jc + jg + 4 * u) * 512 + d];
#pragma unroll
      for (int u = 0; u < 16; ++u) {
        int jj = jg + 4 * u;
        float gw = gsh[jb + jj] * wv[u];
        gs += gw;
        bs = fmaf(bsh[jb + jj], wv[u], bs);
        if (top) tile[jj][dl] = f2bf(gw);
        else uu = fmaf(pm[jb + jj], gw, uu);
      }
      if (top) {
        __syncthreads();
        int dr = t >> 2, q4 = t & 3;
        unsigned o[8];
#pragma unroll
        for (int i = 0; i < 8; ++i) {
          unsigned lo = tile[q4 * 16 + 2 * i][dr];
          unsigned hi = tile[q4 * 16 + 2 * i + 1][dr];
          o[i] = lo | (hi << 16);
        }
        uint4* dst = (uint4*)(gwT + (size_t)(d0 + dr) * C + jc + q4 * 16);
        dst[0] = make_uint4(o[0], o[1], o[2], o[3]);
        dst[1] = make_uint4(o[4], o[5], o[6], o[7]);
        __syncthreads();
      }
    }
    r1[t] = gs; r2[t] = bs; r3[t] = uu;
    __syncthreads();
    if (t < 64) {
      float G = 0.f, Bv = 0.f, U = 0.f;
      for (int k = 0; k < 4; ++k) {
        G += r1[k * 64 + t];
        Bv += r2[k * 64 + t];
        U += r3[k * 64 + t];
      }
      if (seg == 0) Bv += A.bias[l][d0 + t];
      int idx = (l * 4 + seg) * 512 + d0 + t;
      ((float*)(A.ws + OFF_U))[idx] = U;
      ((float*)(A.ws + OFF_GG))[idx] = G;
      ((float*)(A.ws + OFF_BB))[idx] = Bv;
    }
  } else if (bid < 132) {
    // ---- per-level proto sums (sproto, sqproto) ----
    int l = bid - 128;
    int C = 256 << l;
    const float* pr = A.proto[l];
    float s1 = 0.f, s2 = 0.f;
    for (int c = t; c < C; c += 256) {
      const float* pp = pr + c;
      float acc = 0.f;
#pragma unroll
      for (int r = 0; r < 64; ++r) acc += pp[(size_t)r * C];
      float pmv = acc * (1.0f / 64.0f);
      s1 += pmv;
      s2 = fmaf(pmv, pmv, s2);
    }
    r1[t] = s1; r2[t] = s2;
    __syncthreads();
    for (int o = 128; o > 0; o >>= 1) {
      if (t < o) { r1[t] += r1[t + o]; r2[t] += r2[t + o]; }
      __syncthreads();
    }
    if (t == 0) {
      float* scal = (float*)(A.ws + OFF_SCAL);
      scal[l] = r1[0];
      scal[4 + l] = r2[0];
    }
  } else {
    // ---- text l2norm + scale ----
    float* tf = (float*)(A.ws + OFF_TEXT);
    for (int r = 0; r < 8; ++r) {
      float p = 0.f;
      for (int c = t; c < 512; c += 256) {
        float v = A.text[r * 512 + c];
        p += v * v;
      }
      r1[t] = p;
      __syncthreads();
      for (int o = 128; o > 0; o >>= 1) {
        if (t < o) r1[t] += r1[t + o];
        __syncthreads();
      }
      float inv = 1.0f / fmaxf(sqrtf(r1[0]), 1e-12f);
      __syncthreads();
      for (int c = t; c < 512; c += 256) tf[r * 512 + c] = A.text[r * 512 + c] * inv;
    }
    if (t == 0) {
      float s = fmaxf(A.lsc[0], 1e-4f);
      ((float*)(A.ws + OFF_SCAL))[8] = s * 0.04419417382415922f;  // 1/sqrt(512)
    }
  }
}

// ================= gemm2: m97-shape 128x128 bf16 GEMM + LN-fold epilogue =================
__global__ __launch_bounds__(256, 3) void gemm2(char* ws) {
  __shared__ __align__(16) char lds[18944];
  int t = threadIdx.x, bid = blockIdx.x;
  int l = 3 - (bid >> 8);          // heavy levels first
  int rb = (bid >> 2) & 63, cb = bid & 3;
  int C = 256 << l;
  int m0 = rb * 128, n0 = cb * 128;

  float* uArr  = (float*)(lds + 16384);
  float* gArr  = (float*)(lds + 16896);
  float* bArr  = (float*)(lds + 17408);
  float* rowM  = (float*)(lds + 17920);
  float* rowIS = (float*)(lds + 18432);
  const float* scal = (const float*)(ws + OFF_SCAL);

  if (t < 128) {
    float su = 0.f, sg = 0.f, sb = 0.f;
    for (int s = 0; s < 4; ++s) {
      int idx = (l * 4 + s) * 512 + n0 + t;
      su += ((const float*)(ws + OFF_U))[idx];
      sg += ((const float*)(ws + OFF_GG))[idx];
      sb += ((const float*)(ws + OFF_BB))[idx];
    }
    uArr[t] = su; gArr[t] = sg; bArr[t] = sb;
  } else {
    int r = t - 128;
    const float* st = (const float*)(ws + OFF_STAT) + (size_t)(l * 8192 + m0 + r) * 2;
    float s1 = st[0], s2 = st[1];
    float inv2C = 1.0f / (float)(2 * C);
    float mr = (s1 + scal[l]) * inv2C;
    float var = (s2 + scal[4 + l]) * inv2C - mr * mr;
    rowM[r] = mr;
    rowIS[r] = rsqrtf(var + 1e-5f);
  }

  int w = t >> 6, lane = t & 63, quad = lane >> 4, lc = lane & 15;
  const char* Abf = ws + OFF_ABF + abf_off(l);
  const char* Bw  = ws + OFF_GWT + gwt_off(l);
  const char* aP[2]; const char* bP[2];
  char* aD[2]; char* bD[2];
#pragma unroll
  for (int i = 0; i < 2; ++i) {
    int li = i * 256 + t;
    int rr = li >> 2, kq = li & 3;
    aP[i] = Abf + ((size_t)(m0 + rr) * C + kq * 8) * 2;
    bP[i] = Bw  + ((size_t)(n0 + rr) * C + kq * 8) * 2;
    aD[i] = lds + i * 4096 + w * 1024;
    bD[i] = lds + 8192 + i * 4096 + w * 1024;
  }
  int wr = (w >> 1) * 64, wc = (w & 1) * 64;
  const char* aF = lds + (wr + lc) * 64 + quad * 16;
  const char* bF = lds + 8192 + (wc + lc) * 64 + quad * 16;

  f32x4 acc[4][4] = {};
  for (int k0 = 0; k0 < C; k0 += 32) {
    async_load16(aP[0], aD[0]); async_load16(aP[1], aD[1]);
    async_load16(bP[0], bD[0]); async_load16(bP[1], bD[1]);
    aP[0] += 64; aP[1] += 64; bP[0] += 64; bP[1] += 64;
    __syncthreads();
    bf16x8 av[4];
#pragma unroll
    for (int rt = 0; rt < 4; ++rt) av[rt] = *(const bf16x8*)(aF + rt * 1024);
#pragma unroll
    for (int ct = 0; ct < 4; ++ct) {
      bf16x8 bv = *(const bf16x8*)(bF + ct * 1024);
#pragma unroll
      for (int rt = 0; rt < 4; ++rt)
        acc[rt][ct] = __builtin_amdgcn_mfma_f32_16x16x32_bf16(av[rt], bv, acc[rt][ct], 0, 0, 0);
    }
    __syncthreads();
  }

  // epilogue: h = relu((acc + u - m*G)*invs + B) -> bf16 store
  char* Hl = ws + OFF_H + (size_t)l * 8388608;
#pragma unroll
  for (int rt = 0; rt < 4; ++rt) {
#pragma unroll
    for (int ct = 0; ct < 4; ++ct) {
      int nl = wc + ct * 16 + lc;
      float uu = uArr[nl], gg = gArr[nl], bb = bArr[nl];
      f32x4 a = acc[rt][ct];
#pragma unroll
      for (int reg = 0; reg < 4; ++reg) {
        int ml = wr + rt * 16 + quad * 4 + reg;
        float h = fmaf(a[reg] + uu - rowM[ml] * gg, rowIS[ml], bb);
        h = fmaxf(h, 0.f);
        float hp = __shfl_xor(h, 1);
        if (!(lc & 1)) {
          unsigned pkv = pack2(h, hp);
          *(unsigned*)(Hl + ((size_t)(m0 + ml) * 512 + n0 + nl) * 2) = pkv;
        }
      }
    }
  }
}

// ================= postK: l2norm + text dots + softmax =================
__global__ __launch_bounds__(256) void postK(const char* ws, float* out) {
  __shared__ float textL[4096];
  int t = threadIdx.x, b = blockIdx.x;
  const float* tf = (const float*)(ws + OFF_TEXT);
  for (int i = t; i < 4096; i += 256) textL[i] = tf[i];
  __syncthreads();
  float scale = ((const float*)(ws + OFF_SCAL))[8];
  int row = b * 16 + (t >> 4), q = t & 15;
  float lg[4][8];
#pragma unroll
  for (int l = 0; l < 4; ++l) {
    const uint4* hp = (const uint4*)(ws + OFF_H + (size_t)l * 8388608 +
                                     ((size_t)row * 512 + q * 32) * 2);
    float np = 0.f;
    float dp[8] = {};
#pragma unroll
    for (int ch = 0; ch < 4; ++ch) {
      uint4 u = hp[ch];
      int d0 = q * 32 + ch * 8;
      unsigned uw[4] = {u.x, u.y, u.z, u.w};
#pragma unroll
      for (int p = 0; p < 4; ++p) {
        float v0 = __uint_as_float(uw[p] << 16);
        float v1 = __uint_as_float(uw[p] & 0xffff0000u);
        int dd = d0 + p * 2;
        np = fmaf(v0, v0, np);
        np = fmaf(v1, v1, np);
#pragma unroll
        for (int k = 0; k < 8; ++k) {
          dp[k] = fmaf(v0, textL[k * 512 + dd], dp[k]);
          dp[k] = fmaf(v1, textL[k * 512 + dd + 1], dp[k]);
        }
      }
    }
#pragma unroll
    for (int off = 1; off < 16; off <<= 1) {
      np += __shfl_xor(np, off);
#pragma unroll
      for (int k = 0; k < 8; ++k) dp[k] += __shfl_xor(dp[k], off);
    }
    float innorm = scale / fmaxf(sqrtf(np), 1e-12f);
#pragma unroll
    for (int k = 0; k < 8; ++k) lg[l][k] = dp[k] * innorm;
  }
  if (q == 0) {
    float4* op = (float4*)out + (size_t)row * 8;
#pragma unroll
    for (int k = 0; k < 8; ++k) {
      float a = lg[0][k], b2 = lg[1][k], c = lg[2][k], d = lg[3][k];
      float mx = fmaxf(fmaxf(a, b2), fmaxf(c, d));
      float e0 = __expf(a - mx), e1 = __expf(b2 - mx);
      float e2 = __expf(c - mx), e3 = __expf(d - mx);
      float inv = 1.0f / (e0 + e1 + e2 + e3);
      op[k] = make_float4(e0 * inv, e1 * inv, e2 * inv, e3 * inv);
    }
  }
}

extern "C" void kernel_launch(void* const* d_in, const int* in_sizes, int n_in,
                              void* d_out, int out_size, void* d_ws, size_t ws_size,
                              hipStream_t stream) {
  (void)n_in; (void)out_size;
  if (ws_size < (size_t)WS_TOTAL) return;  // loud failure: output stays poisoned
  char* ws = (char*)d_ws;
  bool dict = (in_sizes[1] == 64 * 256);
  PrepArgs pa;
  for (int l = 0; l < 4; ++l) {
    if (dict) {
      pa.pooled[l] = (const float*)d_in[6 * l + 0];
      pa.proto[l]  = (const float*)d_in[6 * l + 1];
      pa.g[l]      = (const float*)d_in[6 * l + 2];
      pa.beta[l]   = (const float*)d_in[6 * l + 3];
      pa.W[l]      = (const float*)d_in[6 * l + 4];
      pa.bias[l]   = (const float*)d_in[6 * l + 5];
    } else {
      pa.pooled[l] = (const float*)d_in[l];
      pa.proto[l]  = (const float*)d_in[4 + l];
      pa.g[l]      = (const float*)d_in[8 + l];
      pa.beta[l]   = (const float*)d_in[12 + l];
      pa.W[l]      = (const float*)d_in[16 + l];
      pa.bias[l]   = (const float*)d_in[20 + l];
    }
  }
  pa.text = (const float*)d_in[24];
  pa.lsc = (const float*)d_in[25];
  pa.ws = ws;

  prep<<<3973, 256, 24576, stream>>>(pa);
  gemm2<<<1024, 256, 0, stream>>>(ws);
  postK<<<512, 256, 0, stream>>>(ws, (float*)d_out);
}